// Round 6
// baseline (516.052 us; speedup 1.0000x reference)
//
#include <hip/hip_runtime.h>
#include <hip/hip_bf16.h>

#define NPOS 784
#define WDIM 28
#define QB   8     // queries per block
#define NQT  98    // NPOS / QB

// ---- bf16 pack/unpack helpers (RNE) ----
__device__ __forceinline__ unsigned int f2bf(float f) {
    union { float f; unsigned int u; } v; v.f = f;
    unsigned int r = v.u + 0x7fffu + ((v.u >> 16) & 1u);
    return r >> 16;                                  // bf16 bits in low 16
}
__device__ __forceinline__ float bflo(unsigned int p) {
    union { unsigned int u; float f; } v; v.u = p << 16; return v.f;
}
__device__ __forceinline__ float bfhi(unsigned int p) {
    union { unsigned int u; float f; } v; v.u = p & 0xffff0000u; return v.f;
}

// ---------------- kernel 1: fused 1x1-conv q/k/v -> d_ws, + bias-init of out ----
// Q/K/V fp32, layout [bh][kl][m] (m contiguous). out pre-filled with b_out
// (attention kernel accumulates its projection via atomicAdd).
__global__ __launch_bounds__(256) void qkv_kernel(
    const float* __restrict__ x,
    const float* __restrict__ wq, const float* __restrict__ bq,
    const float* __restrict__ wk, const float* __restrict__ bk,
    const float* __restrict__ wv, const float* __restrict__ bv,
    const float* __restrict__ b_out,
    float* __restrict__ Q, float* __restrict__ K, float* __restrict__ V,
    float* __restrict__ out)
{
    int idx = blockIdx.x * 256 + threadIdx.x;        // grid covers exactly 401408
    int ij = idx % NPOS;
    int oc = (idx / NPOS) & 127;
    int b  = idx / (NPOS * 128);

    float x0 = x[(b * 3 + 0) * NPOS + ij];
    float x1 = x[(b * 3 + 1) * NPOS + ij];
    float x2 = x[(b * 3 + 2) * NPOS + ij];

    float q = bq[oc] + wq[oc*3+0]*x0 + wq[oc*3+1]*x1 + wq[oc*3+2]*x2;
    float k = bk[oc] + wk[oc*3+0]*x0 + wk[oc*3+1]*x1 + wk[oc*3+2]*x2;
    float v = bv[oc] + wv[oc*3+0]*x0 + wv[oc*3+1]*x1 + wv[oc*3+2]*x2;

    int m = oc >> 3, h = oc & 7;                     // oc = m*HEADS + h
    int dst = ((b * 8 + h) * NPOS + ij) * 16 + m;
    Q[dst] = q; K[dst] = k; V[dst] = v;

    // bias-init the atomic-accumulation output (covers all 802816 elements)
    for (int e = idx; e < 4 * 64 * 4 * NPOS; e += 401408) {
        int o = (e / (4 * NPOS)) & 63;
        out[e] = b_out[o];
    }
}

// ---------------- kernel 2: attention, block = (b, h, 8-query tile) ----------------
__global__ __launch_bounds__(256, 2) void attn_kernel(
    const float* __restrict__ Q, const float* __restrict__ K, const float* __restrict__ V,
    const float* __restrict__ w_out,
    const float* __restrict__ rw1, const float* __restrict__ rb1,
    const float* __restrict__ rga, const float* __restrict__ rbe,
    const float* __restrict__ rw2, const float* __restrict__ rb2,
    const float* __restrict__ cw1, const float* __restrict__ cb1,
    const float* __restrict__ cga, const float* __restrict__ cbe,
    const float* __restrict__ cw2, const float* __restrict__ cb2,
    float* __restrict__ out)
{
    __shared__ unsigned int Kpk[8][788];             // bf16x2 pairs: m = 2mp, 2mp+1
    __shared__ unsigned int Vpk[8][788];
    __shared__ __align__(16) float contbuf[3136];    // phase0-1: E tables fp32[1760]; then cont bf16[8][784]
    __shared__ float4 Rt[8][56];                     // (s*arow[d], s*acol[d], s*arow[d+55], s*acol[d+55]); [55] pad
    __shared__ float  qs[8][16];
    __shared__ float4 Mq4[8];
    __shared__ __align__(16) float ovs[8][4][16];

    const int t   = threadIdx.x;
    const int bh  = blockIdx.x / NQT;
    const int qt  = blockIdx.x % NQT;
    const int b   = bh >> 3, h = bh & 7;
    const int ij0 = qt * QB;
    const float scale = 0.57735026918962576f;        // 1/sqrt(CIN=3)

    // ---- phase 0: stage K/V (packed bf16), embed-MLP tables, q tile ----
    {
        const float* Kg = K + bh * (NPOS * 16);
        const float* Vg = V + bh * (NPOS * 16);
        for (int e = t; e < NPOS * 4; e += 256) {    // e over float4 quads, coalesced
            int k = e >> 2, mq = e & 3;
            float4 kv = ((const float4*)(Kg + k * 16))[mq];
            Kpk[2*mq  ][k] = f2bf(kv.x) | (f2bf(kv.y) << 16);
            Kpk[2*mq+1][k] = f2bf(kv.z) | (f2bf(kv.w) << 16);
            float4 vv = ((const float4*)(Vg + k * 16))[mq];
            Vpk[2*mq  ][k] = f2bf(vv.x) | (f2bf(vv.y) << 16);
            Vpk[2*mq+1][k] = f2bf(vv.z) | (f2bf(vv.w) << 16);
        }
        if (t < 128) qs[t >> 4][t & 15] = Q[(bh * NPOS + ij0 + (t >> 4)) * 16 + (t & 15)];

        // embed MLP -> Efp (aliases contbuf; consumed by R-build before cont overwrites)
        int d = -1;
        const float *w1 = rw1, *b1 = rb1, *ga = rga, *be = rbe, *w2 = rw2, *b2 = rb2;
        float* E = contbuf;                          // row table at [0,880)
        if (t < 110) { d = t; }
        else if (t >= 128 && t < 238) { d = t - 128; w1 = cw1; b1 = cb1; ga = cga; be = cbe; w2 = cw2; b2 = cb2; E = contbuf + 880; }
        if (d >= 0) {
            float u = (d < 55) ? (-1.0f + (float)d * (2.0f / 54.0f))
                               : -(-1.0f + (float)(d - 55) * (2.0f / 54.0f));
            float hb[16], mu = 0.0f;
#pragma unroll
            for (int c = 0; c < 16; ++c) { hb[c] = u * w1[c] + b1[c]; mu += hb[c]; }
            mu *= (1.0f / 16.0f);
            float var = 0.0f;
#pragma unroll
            for (int c = 0; c < 16; ++c) { float dv = hb[c] - mu; var += dv * dv; }
            var *= (1.0f / 16.0f);
            float rstd = rsqrtf(var + 1e-5f);
#pragma unroll
            for (int c = 0; c < 16; ++c) {
                float hn = ga[c] * (hb[c] - mu) * rstd + be[c];
                hb[c] = hn / (1.0f + __expf(-hn));
            }
#pragma unroll
            for (int m = 0; m < 8; ++m) {
                float e = b2[m];
#pragma unroll
                for (int c = 0; c < 16; ++c) e += hb[c] * w2[m * 16 + c];
                E[d * 8 + m] = e;
            }
        }
    }
    __syncthreads();

    // ---- phase 1: packed rotation table Rt[q][d] ----
    for (int p = t; p < 440; p += 256) {             // 8 q x 55 d
        int q = (p * 1192) >> 16;                    // p / 55
        int d = p - q * 55;
        const float* Er = contbuf;
        const float* Ec = contbuf + 880;
        float ar = 0, ac = 0, ar5 = 0, ac5 = 0;
#pragma unroll
        for (int mm = 0; mm < 8; ++mm) {
            float ql = qs[q][mm], qh = qs[q][8 + mm];
            ar  += ql * Er[d * 8 + mm];
            ar5 += ql * Er[(d + 55) * 8 + mm];
            ac  += qh * Ec[d * 8 + mm];
            ac5 += qh * Ec[(d + 55) * 8 + mm];
        }
        Rt[q][d] = make_float4(ar * scale, ac * scale, ar5 * scale, ac5 * scale);
    }
    __syncthreads();

    // ---- phase 2: content pass (overwrites E region with bf16 cont) ----
    unsigned short* cont = (unsigned short*)contbuf;
    {
        int quad = t >> 7;                           // 2 quads of 4 queries
        int u = t & 127;
        float qr[4][16];
#pragma unroll
        for (int qq = 0; qq < 4; ++qq)
#pragma unroll
            for (int m = 0; m < 16; ++m) qr[qq][m] = qs[quad * 4 + qq][m];
        for (int k = u; k < NPOS; k += 128) {
            float c0 = 0, c1 = 0, c2v = 0, c3 = 0;
#pragma unroll
            for (int mp = 0; mp < 8; ++mp) {
                unsigned int pk = Kpk[mp][k];
                float klo = bflo(pk), khi = bfhi(pk);
                c0  += qr[0][2*mp] * klo + qr[0][2*mp+1] * khi;
                c1  += qr[1][2*mp] * klo + qr[1][2*mp+1] * khi;
                c2v += qr[2][2*mp] * klo + qr[2][2*mp+1] * khi;
                c3  += qr[3][2*mp] * klo + qr[3][2*mp+1] * khi;
            }
            cont[(quad * 4 + 0) * NPOS + k] = (unsigned short)f2bf(c0  * scale);
            cont[(quad * 4 + 1) * NPOS + k] = (unsigned short)f2bf(c1  * scale);
            cont[(quad * 4 + 2) * NPOS + k] = (unsigned short)f2bf(c2v * scale);
            cont[(quad * 4 + 3) * NPOS + k] = (unsigned short)f2bf(c3  * scale);
        }
    }
    __syncthreads();

    // ---- phase 3: per-(q,g) max ----
    {
        int q = t >> 5, u = t & 31;
        int ij_q = ij0 + q;
        int iq = ij_q / WDIM, jq = ij_q - iq * WDIM;
        int k0, n;
        if (u < 16) { k0 = u * 25; n = 25; } else { k0 = 400 + (u - 16) * 24; n = 24; }
        int row = k0 / WDIM, col = k0 - row * WDIM;
        float4 rr = Rt[q][row - iq + 27];
        float m0 = -3.4e38f, m1 = -3.4e38f, m2 = -3.4e38f, m3 = -3.4e38f;
        int k = k0;
        for (int s = 0; s < n; ++s, ++k) {
            float c = bflo((unsigned int)cont[q * NPOS + k]);
            float4 rc = Rt[q][col - jq + 27];
            m0 = fmaxf(m0, c + rr.x + rc.y);
            m1 = fmaxf(m1, c + rr.y + rc.z);
            m2 = fmaxf(m2, c + rr.z + rc.w);
            m3 = fmaxf(m3, c + rr.w + rc.x);
            if (++col == WDIM) { col = 0; ++row; rr = Rt[q][row - iq + 27]; }
        }
#pragma unroll
        for (int off = 16; off; off >>= 1) {
            m0 = fmaxf(m0, __shfl_down(m0, off, 32));
            m1 = fmaxf(m1, __shfl_down(m1, off, 32));
            m2 = fmaxf(m2, __shfl_down(m2, off, 32));
            m3 = fmaxf(m3, __shfl_down(m3, off, 32));
        }
        if (u == 0) Mq4[q] = make_float4(m0, m1, m2, m3);
    }
    __syncthreads();

    // ---- phase 4: exp + PV (single exp per (q,g,k)), width-32 reduce ----
    {
        int q = t >> 5, u = t & 31;
        int ij_q = ij0 + q;
        int iq = ij_q / WDIM, jq = ij_q - iq * WDIM;
        int k0, n;
        if (u < 16) { k0 = u * 25; n = 25; } else { k0 = 400 + (u - 16) * 24; n = 24; }
        float4 M = Mq4[q];
        float acc[4][16];
#pragma unroll
        for (int g = 0; g < 4; ++g)
#pragma unroll
            for (int m = 0; m < 16; ++m) acc[g][m] = 0.0f;
        float ps0 = 0, ps1 = 0, ps2 = 0, ps3 = 0;
        int row = k0 / WDIM, col = k0 - row * WDIM;
        float4 rr = Rt[q][row - iq + 27];
        int k = k0;
        for (int s = 0; s < n; ++s, ++k) {
            float c = bflo((unsigned int)cont[q * NPOS + k]);
            float4 rc = Rt[q][col - jq + 27];
            float p0 = __expf(c + rr.x + rc.y - M.x);
            float p1 = __expf(c + rr.y + rc.z - M.y);
            float p2 = __expf(c + rr.z + rc.w - M.z);
            float p3 = __expf(c + rr.w + rc.x - M.w);
            ps0 += p0; ps1 += p1; ps2 += p2; ps3 += p3;
#pragma unroll
            for (int mp = 0; mp < 8; ++mp) {
                unsigned int pv = Vpk[mp][k];
                float v0 = bflo(pv), v1 = bfhi(pv);
                acc[0][2*mp] += p0 * v0; acc[0][2*mp+1] += p0 * v1;
                acc[1][2*mp] += p1 * v0; acc[1][2*mp+1] += p1 * v1;
                acc[2][2*mp] += p2 * v0; acc[2][2*mp+1] += p2 * v1;
                acc[3][2*mp] += p3 * v0; acc[3][2*mp+1] += p3 * v1;
            }
            if (++col == WDIM) { col = 0; ++row; rr = Rt[q][row - iq + 27]; }
        }
#pragma unroll
        for (int off = 16; off; off >>= 1) {
            ps0 += __shfl_down(ps0, off, 32); ps1 += __shfl_down(ps1, off, 32);
            ps2 += __shfl_down(ps2, off, 32); ps3 += __shfl_down(ps3, off, 32);
        }
#pragma unroll
        for (int g = 0; g < 4; ++g)
#pragma unroll
            for (int m = 0; m < 16; ++m)
#pragma unroll
                for (int off = 16; off; off >>= 1)
                    acc[g][m] += __shfl_down(acc[g][m], off, 32);
        if (u == 0) {
            float inv[4] = {1.0f / ps0, 1.0f / ps1, 1.0f / ps2, 1.0f / ps3};
#pragma unroll
            for (int g = 0; g < 4; ++g)
#pragma unroll
                for (int m = 0; m < 16; ++m) ovs[q][g][m] = acc[g][m] * inv[g];
        }
    }
    __syncthreads();

    // ---- phase 5: output projection for this head, atomic accumulate ----
    {
        int o = t >> 2, g = t & 3;
        float wo[16];
#pragma unroll
        for (int mm = 0; mm < 16; ++mm) wo[mm] = w_out[o * 128 + mm * 8 + h];
        for (int q = 0; q < QB; ++q) {
            const float* ov = ovs[q][g];
            float a = 0.0f;
#pragma unroll
            for (int mm = 0; mm < 16; ++mm) a += wo[mm] * ov[mm];
            atomicAdd(out + ((b * 64 + o) * 4 + g) * NPOS + ij0 + q, a);
        }
    }
}

extern "C" void kernel_launch(void* const* d_in, const int* in_sizes, int n_in,
                              void* d_out, int out_size, void* d_ws, size_t ws_size,
                              hipStream_t stream)
{
    const float* x     = (const float*)d_in[0];
    const float* wq    = (const float*)d_in[1];
    const float* bq    = (const float*)d_in[2];
    const float* wk    = (const float*)d_in[3];
    const float* bk    = (const float*)d_in[4];
    const float* wv    = (const float*)d_in[5];
    const float* bv    = (const float*)d_in[6];
    const float* w_out = (const float*)d_in[7];
    const float* b_out = (const float*)d_in[8];
    const float* rw1 = (const float*)d_in[9];
    const float* rb1 = (const float*)d_in[10];
    const float* rga = (const float*)d_in[11];
    const float* rbe = (const float*)d_in[12];
    const float* rw2 = (const float*)d_in[13];
    const float* rb2 = (const float*)d_in[14];
    const float* cw1 = (const float*)d_in[15];
    const float* cb1 = (const float*)d_in[16];
    const float* cga = (const float*)d_in[17];
    const float* cbe = (const float*)d_in[18];
    const float* cw2 = (const float*)d_in[19];
    const float* cb2 = (const float*)d_in[20];
    // d_in[21]/d_in[22] (ridx/cidx) unused: closed-form rotation indices.

    float* Q = (float*)d_ws;                 // 3 x 401408 floats = 4.8 MB (proven available in round 5)
    float* K = Q + 401408;
    float* V = K + 401408;

    qkv_kernel<<<1568, 256, 0, stream>>>(x, wq, bq, wk, bk, wv, bv, b_out,
                                         Q, K, V, (float*)d_out);
    attn_kernel<<<32 * NQT, 256, 0, stream>>>(
        Q, K, V, w_out,
        rw1, rb1, rga, rbe, rw2, rb2,
        cw1, cb1, cga, cbe, cw2, cb2,
        (float*)d_out);
}